// Round 4
// baseline (358.211 us; speedup 1.0000x reference)
//
#include <hip/hip_runtime.h>
#include <hip/hip_bf16.h>
#include <math.h>

#define TOK 8192       // B*S
#define DIM 256
#define SEQ 1024
#define NH 8
#define FFD 1024
#define NL 2
#define VOCAB 32000

typedef short bf16x8 __attribute__((ext_vector_type(8)));
typedef short bf16x4 __attribute__((ext_vector_type(4)));
typedef float f32x4 __attribute__((ext_vector_type(4)));

__device__ __forceinline__ ushort f2bf(float f) {
  union { float f; uint32_t u; } v; v.f = f;
  uint32_t r = v.u + 0x7FFFu + ((v.u >> 16) & 1u);
  return (ushort)(r >> 16);
}

__device__ __forceinline__ float exp2_n(float x) {
  float r; asm("v_exp_f32 %0, %1" : "=v"(r) : "v"(x)); return r;
}

__device__ __forceinline__ void gload_lds16(const ushort* gp, ushort* lp) {
  __builtin_amdgcn_global_load_lds(
      (const __attribute__((address_space(1))) void*)gp,
      (__attribute__((address_space(3))) void*)lp, 16, 0, 0);
}

// ---------------- embedding + ngram + per-layer base-2 tfidf bias ----------------
__global__ __launch_bounds__(256) void embed_kernel(
    const int* __restrict__ ids, const int* __restrict__ ngram_ids,
    const float* __restrict__ tfidf, const float* __restrict__ emb,
    const float* __restrict__ pos, const float* __restrict__ bucket,
    const float* __restrict__ alpha, float* __restrict__ x, float* __restrict__ bm2)
{
  __shared__ int ngs[12];
  const int t = blockIdx.x;
  const int id = ids[t];
  int idc = id; if (idc < 0) idc = 0; if (idc > VOCAB-1) idc = VOCAB-1;
  if (threadIdx.x < 12) ngs[threadIdx.x] = ngram_ids[idc*12 + threadIdx.x];
  if (threadIdx.x == 0) {
    const float tf = tfidf[idc];
    const bool msk = (id == 0);
    const float l2e = 1.4426950408889634f;
    bm2[t]       = msk ? -1e30f : tf * alpha[0] * l2e;
    bm2[TOK + t] = msk ? -1e30f : tf * alpha[1] * l2e;
  }
  __syncthreads();
  const int d = threadIdx.x;
  const int s = t & (SEQ - 1);
  float v = emb[(size_t)id*DIM + d] + pos[s*DIM + d];
  float sum = 0.f; int cnt = 0;
  #pragma unroll
  for (int g = 0; g < 12; ++g) {
    const int ng = ngs[g];
    if (ng != 0) { sum += bucket[(size_t)ng*DIM + d]; cnt++; }
  }
  v += sum / fmaxf((float)cnt, 1.0f);
  x[(size_t)t*DIM + d] = v;
}

// ---------------- layernorm -> bf16 ----------------
__global__ __launch_bounds__(256) void ln_bf16(
    const float* __restrict__ x, const float* __restrict__ g,
    const float* __restrict__ b, ushort* __restrict__ y)
{
  const int wave = threadIdx.x >> 6, lane = threadIdx.x & 63;
  const int row = blockIdx.x * 4 + wave;
  const float* xr = x + (size_t)row * DIM;
  float4 v = *reinterpret_cast<const float4*>(xr + lane*4);
  float s = v.x + v.y + v.z + v.w;
  #pragma unroll
  for (int o = 32; o >= 1; o >>= 1) s += __shfl_xor(s, o);
  const float mean = s * (1.f/256.f);
  const float dx0 = v.x-mean, dx1 = v.y-mean, dx2 = v.z-mean, dx3 = v.w-mean;
  float q = dx0*dx0 + dx1*dx1 + dx2*dx2 + dx3*dx3;
  #pragma unroll
  for (int o = 32; o >= 1; o >>= 1) q += __shfl_xor(q, o);
  const float rs = rsqrtf(q * (1.f/256.f) + 1e-5f);
  float4 gv = *reinterpret_cast<const float4*>(g + lane*4);
  float4 bv = *reinterpret_cast<const float4*>(b + lane*4);
  ushort4 o4;
  o4.x = f2bf(dx0*rs*gv.x + bv.x);
  o4.y = f2bf(dx1*rs*gv.y + bv.y);
  o4.z = f2bf(dx2*rs*gv.z + bv.z);
  o4.w = f2bf(dx3*rs*gv.w + bv.w);
  *reinterpret_cast<ushort4*>(y + (size_t)row*DIM + lane*4) = o4;
}

// ---------------- weight transpose + bf16: f32 [K][N] -> bf16 [N][K] ----------------
struct TDesc { const float* src; ushort* dst; int K; int N; };
struct TDescs { TDesc d[12]; };

__global__ __launch_bounds__(256) void transpose_conv(TDescs descs)
{
  const TDesc t = descs.d[blockIdx.z];
  const int k0 = blockIdx.x * 32, n0 = blockIdx.y * 32;
  if (k0 >= t.K || n0 >= t.N) return;
  __shared__ float tile[32][33];
  const int r = threadIdx.x >> 5, cc = threadIdx.x & 31;
  #pragma unroll
  for (int i = 0; i < 4; ++i)
    tile[r + i*8][cc] = t.src[(size_t)(k0 + r + i*8)*t.N + n0 + cc];
  __syncthreads();
  #pragma unroll
  for (int i = 0; i < 4; ++i)
    t.dst[(size_t)(n0 + r + i*8)*t.K + k0 + cc] = f2bf(tile[cc][r + i*8]);
}

// ---------------- bf16 MFMA GEMM: C[M,N] = A[M,K] @ B^T  (B as [N][K]) ----------------
// BM=64, BN=128, BK=32; 4 waves, wave w owns cols [w*32, w*32+32); frags 4x2.
// MODE 1: relu + bf16 out; MODE 2: f32 += ; MODE 3: qkv -> Q,K (stride 512) + V transposed.
template<int KDIM, int NDIM, int MODE>
__global__ __launch_bounds__(256) void gemm_mfma(
    const ushort* __restrict__ A, const ushort* __restrict__ Bw,
    const float* __restrict__ bias0, const float* __restrict__ bias1,
    const float* __restrict__ bias2, void* __restrict__ Cout,
    ushort* __restrict__ vtb)
{
  __shared__ ushort Al[2][64*32];
  __shared__ ushort Bl[2][128*32];
  const int bm = blockIdx.y * 64, bn = blockIdx.x * 128;
  const int tid = threadIdx.x, w = tid >> 6, lane = tid & 63;
  const int g = lane >> 4, c = lane & 15;
  const int lrow = lane >> 2, lc8 = (lane & 3) * 8;
  const f32x4 fzero = {0.f, 0.f, 0.f, 0.f};
  f32x4 acc[4][2];
  #pragma unroll
  for (int m = 0; m < 4; ++m) { acc[m][0] = fzero; acc[m][1] = fzero; }

#define STAGE(buf, k0)                                                         \
  {                                                                            \
    _Pragma("unroll")                                                          \
    for (int ch = w; ch < 12; ch += 4) {                                       \
      if (ch < 4)                                                              \
        gload_lds16(A + (size_t)(bm + ch*16 + lrow)*KDIM + (k0) + lc8,         \
                    &Al[buf][ch*512]);                                         \
      else                                                                     \
        gload_lds16(Bw + (size_t)(bn + (ch-4)*16 + lrow)*KDIM + (k0) + lc8,    \
                    &Bl[buf][(ch-4)*512]);                                     \
    }                                                                          \
  }

  STAGE(0, 0);
  asm volatile("s_waitcnt vmcnt(0)");
  __syncthreads();
  int buf = 0;
  for (int k0 = 0; k0 < KDIM; k0 += 32) {
    if (k0 + 32 < KDIM) STAGE(buf^1, k0 + 32);
    bf16x8 af[4], bfr[2];
    #pragma unroll
    for (int m = 0; m < 4; ++m)
      af[m] = *(const bf16x8*)&Al[buf][(m*16 + c)*32 + g*8];
    #pragma unroll
    for (int n = 0; n < 2; ++n)
      bfr[n] = *(const bf16x8*)&Bl[buf][(w*32 + n*16 + c)*32 + g*8];
    #pragma unroll
    for (int m = 0; m < 4; ++m)
      #pragma unroll
      for (int n = 0; n < 2; ++n)
        acc[m][n] = __builtin_amdgcn_mfma_f32_16x16x32_bf16(af[m], bfr[n], acc[m][n], 0, 0, 0);
    asm volatile("s_waitcnt vmcnt(0)");
    __syncthreads();
    buf ^= 1;
  }
#undef STAGE

  #pragma unroll
  for (int m = 0; m < 4; ++m) {
    const int row0 = bm + m*16 + g*4;
    #pragma unroll
    for (int n = 0; n < 2; ++n) {
      const int col = bn + w*32 + n*16 + c;
      if (MODE == 2) {
        float* C = (float*)Cout;
        const float bb = bias0[col];
        #pragma unroll
        for (int r = 0; r < 4; ++r)
          C[(size_t)(row0 + r)*NDIM + col] += acc[m][n][r] + bb;
      } else if (MODE == 1) {
        const float bb = bias0[col];
        #pragma unroll
        for (int r = 0; r < 4; ++r) {
          const float vv = fmaxf(acc[m][n][r] + bb, 0.f);
          const float other = __shfl_xor(vv, 1);
          if ((c & 1) == 0) {
            const uint32_t word = (uint32_t)f2bf(vv) | ((uint32_t)f2bf(other) << 16);
            *(uint32_t*)((ushort*)Cout + (size_t)(row0 + r)*NDIM + col) = word;
          }
        }
      } else {  // MODE 3
        if (col < 512) {
          const float bb = (col < 256) ? bias0[col] : bias1[col - 256];
          #pragma unroll
          for (int r = 0; r < 4; ++r) {
            const float vv = acc[m][n][r] + bb;
            const float other = __shfl_xor(vv, 1);
            if ((c & 1) == 0) {
              const uint32_t word = (uint32_t)f2bf(vv) | ((uint32_t)f2bf(other) << 16);
              *(uint32_t*)((ushort*)Cout + (size_t)(row0 + r)*512 + col) = word;
            }
          }
        } else {
          const int hd = col - 512;
          const int hh = hd >> 5, d = hd & 31;
          const float bb = bias2[hd];
          const int b_ = row0 >> 10, s = row0 & (SEQ - 1);
          ushort4 w4;
          w4.x = f2bf(acc[m][n][0] + bb);
          w4.y = f2bf(acc[m][n][1] + bb);
          w4.z = f2bf(acc[m][n][2] + bb);
          w4.w = f2bf(acc[m][n][3] + bb);
          *(ushort4*)(vtb + ((size_t)((b_*NH + hh)*32 + d) << 10) + s) = w4;
        }
      }
    }
  }
}

// ---------------- swapped-operand MFMA flash attention (no LDS, no barriers) ----------------
// grid (SEQ/64, NH, B); 4 waves, each wave owns 16 q-rows (q = lane&15).
// QK^T computed as mfma(K,Q): lane (g,c) holds scores[key=kt+ks*16+g*4+r][q=c]
//   -> softmax max/sum are lane-local reg trees + 2 shfl_xor (g-lanes).
// PV computed as mfma(V^T, P) with a custom (consistent) k-slot->key ordering so the
//   P fragment is each lane's own registers: k-slot (g,j) of slice sg = key
//   32*sg + 16*(j>>2) + 4*g + (j&3). V fragment loaded with the same ordering.
// Output D[row=d, col=q=c]: rescale and 1/l divide are lane-local.
__global__ __launch_bounds__(256) void attn_mfma(
    const ushort* __restrict__ qk, const ushort* __restrict__ vt,
    const float* __restrict__ bm2l, ushort* __restrict__ O)
{
  const int qb = blockIdx.x * 64;
  const int h  = blockIdx.y;
  const int b  = blockIdx.z;
  const float scale2 = 0.17677669529663687f * 1.4426950408889634f;  // rsqrt(32)*log2e
  const int tid = threadIdx.x, w = tid >> 6, lane = tid & 63;
  const int g = lane >> 4, c = lane & 15;
  const f32x4 fzero = {0.f, 0.f, 0.f, 0.f};

  const bf16x8 qf = *(const bf16x8*)(qk + (size_t)(b*SEQ + qb + w*16 + c)*512 + h*32 + g*8);
  const ushort* kbase = qk + (size_t)b*SEQ*512 + 256 + h*32 + g*8;      // + key*512
  const ushort* vrow  = vt + ((size_t)((b*NH + h)*32) + c)*SEQ + g*4;   // + ds*16*SEQ + s
  const float*  bmb   = bm2l + b*SEQ;

  f32x4 oacc[2]; oacc[0] = fzero; oacc[1] = fzero;
  float m_run = -1e30f, l_run = 0.f;

  bf16x8 kfA[4], kfB[4];
  bf16x8 vfA[2][2], vfB[2][2];
  f32x4 bbA[4], bbB[4];

#define LOADT(kt, kf, vf, bb)                                                  \
  {                                                                            \
    _Pragma("unroll")                                                          \
    for (int ks = 0; ks < 4; ++ks) {                                           \
      kf[ks] = *(const bf16x8*)(kbase + (size_t)((kt) + ks*16 + c)*512);       \
      bb[ks] = *(const f32x4*)(bmb + (kt) + ks*16 + g*4);                      \
    }                                                                          \
    _Pragma("unroll")                                                          \
    for (int ds_ = 0; ds_ < 2; ++ds_)                                          \
      _Pragma("unroll")                                                        \
      for (int sg = 0; sg < 2; ++sg) {                                         \
        const ushort* vp = vrow + (size_t)ds_*16*SEQ + (kt) + sg*32;           \
        const bf16x4 lo = *(const bf16x4*)(vp);                                \
        const bf16x4 hi = *(const bf16x4*)(vp + 16);                           \
        vf[ds_][sg] = __builtin_shufflevector(lo, hi, 0,1,2,3,4,5,6,7);        \
      }                                                                        \
  }

#define ATILE(kf, vf, bb)                                                      \
  {                                                                            \
    f32x4 sf[4];                                                               \
    _Pragma("unroll")                                                          \
    for (int ks = 0; ks < 4; ++ks)                                             \
      sf[ks] = __builtin_amdgcn_mfma_f32_16x16x32_bf16(kf[ks], qf, fzero, 0, 0, 0); \
    float p[4][4];                                                             \
    _Pragma("unroll")                                                          \
    for (int ks = 0; ks < 4; ++ks)                                             \
      _Pragma("unroll")                                                        \
      for (int r = 0; r < 4; ++r)                                              \
        p[ks][r] = fmaf(sf[ks][r], scale2, bb[ks][r]);                         \
    float tmax = p[0][0];                                                      \
    _Pragma("unroll")                                                          \
    for (int ks = 0; ks < 4; ++ks)                                             \
      _Pragma("unroll")                                                        \
      for (int r = 0; r < 4; ++r)                                              \
        if (ks + r) tmax = fmaxf(tmax, p[ks][r]);                              \
    tmax = fmaxf(tmax, __shfl_xor(tmax, 16));                                  \
    tmax = fmaxf(tmax, __shfl_xor(tmax, 32));                                  \
    const float m_new = fmaxf(m_run, tmax);                                    \
    const float sc = exp2_n(m_run - m_new);                                    \
    m_run = m_new;                                                             \
    float lsum = 0.f;                                                          \
    bf16x8 pb0, pb1;                                                           \
    _Pragma("unroll")                                                          \
    for (int ks = 0; ks < 2; ++ks)                                             \
      _Pragma("unroll")                                                        \
      for (int r = 0; r < 4; ++r) {                                            \
        const float e = exp2_n(p[ks][r] - m_new);                              \
        lsum += e;                                                             \
        pb0[ks*4 + r] = (short)f2bf(e);                                        \
      }                                                                        \
    _Pragma("unroll")                                                          \
    for (int ks = 2; ks < 4; ++ks)                                             \
      _Pragma("unroll")                                                        \
      for (int r = 0; r < 4; ++r) {                                            \
        const float e = exp2_n(p[ks][r] - m_new);                              \
        lsum += e;                                                             \
        pb1[(ks-2)*4 + r] = (short)f2bf(e);                                    \
      }                                                                        \
    lsum += __shfl_xor(lsum, 16);                                              \
    lsum += __shfl_xor(lsum, 32);                                              \
    l_run = l_run * sc + lsum;                                                 \
    oacc[0] *= sc; oacc[1] *= sc;                                              \
    oacc[0] = __builtin_amdgcn_mfma_f32_16x16x32_bf16(vf[0][0], pb0, oacc[0], 0, 0, 0); \
    oacc[1] = __builtin_amdgcn_mfma_f32_16x16x32_bf16(vf[1][0], pb0, oacc[1], 0, 0, 0); \
    oacc[0] = __builtin_amdgcn_mfma_f32_16x16x32_bf16(vf[0][1], pb1, oacc[0], 0, 0, 0); \
    oacc[1] = __builtin_amdgcn_mfma_f32_16x16x32_bf16(vf[1][1], pb1, oacc[1], 0, 0, 0); \
  }

  LOADT(0, kfA, vfA, bbA);
  for (int kt = 0; kt < SEQ; kt += 128) {
    LOADT(kt + 64, kfB, vfB, bbB);
    ATILE(kfA, vfA, bbA);
    if (kt + 128 < SEQ) LOADT(kt + 128, kfA, vfA, bbA);
    ATILE(kfB, vfB, bbB);
  }
#undef LOADT
#undef ATILE

  // epilogue: lane (g,c) holds O[d = ds*16 + g*4 + r][q = c]
  const float inv = 1.f / l_run;
  ushort* orow = O + (size_t)(b*SEQ + qb + w*16 + c)*DIM + h*32 + g*4;
  #pragma unroll
  for (int ds_ = 0; ds_ < 2; ++ds_) {
    const uint32_t w0 = (uint32_t)f2bf(oacc[ds_][0]*inv) | ((uint32_t)f2bf(oacc[ds_][1]*inv) << 16);
    const uint32_t w1 = (uint32_t)f2bf(oacc[ds_][2]*inv) | ((uint32_t)f2bf(oacc[ds_][3]*inv) << 16);
    *(uint32_t*)(orow + ds_*16)     = w0;
    *(uint32_t*)(orow + ds_*16 + 2) = w1;
  }
}

// ---------------- final LN (row 0 per batch) + classifier ----------------
__global__ __launch_bounds__(256) void cls_kernel(
    const float* __restrict__ x, const float* __restrict__ gf,
    const float* __restrict__ bf, const float* __restrict__ Wc,
    const float* __restrict__ bc, float* __restrict__ out)
{
  const int b = blockIdx.x;
  const int tid = threadIdx.x;
  const int wave = tid >> 6, lane = tid & 63;
  const float* xr = x + (size_t)b * SEQ * DIM;
  const float v = xr[tid];
  __shared__ float redm[4], redv[4], redc[4][4];
  float s = v;
  #pragma unroll
  for (int o = 32; o >= 1; o >>= 1) s += __shfl_xor(s, o);
  if (lane == 0) redm[wave] = s;
  __syncthreads();
  const float mean = (redm[0]+redm[1]+redm[2]+redm[3]) * (1.f/256.f);
  const float dv = v - mean;
  float q = dv * dv;
  #pragma unroll
  for (int o = 32; o >= 1; o >>= 1) q += __shfl_xor(q, o);
  if (lane == 0) redv[wave] = q;
  __syncthreads();
  const float var = (redv[0]+redv[1]+redv[2]+redv[3]) * (1.f/256.f);
  const float rs = rsqrtf(var + 1e-5f);
  const float yn = dv*rs*gf[tid] + bf[tid];
  float pc[4];
  #pragma unroll
  for (int cc = 0; cc < 4; ++cc) pc[cc] = yn * Wc[tid*4 + cc];
  #pragma unroll
  for (int cc = 0; cc < 4; ++cc) {
    #pragma unroll
    for (int o = 32; o >= 1; o >>= 1) pc[cc] += __shfl_xor(pc[cc], o);
  }
  if (lane == 0) {
    #pragma unroll
    for (int cc = 0; cc < 4; ++cc) redc[wave][cc] = pc[cc];
  }
  __syncthreads();
  if (tid < 4)
    out[b*4 + tid] = redc[0][tid] + redc[1][tid] + redc[2][tid] + redc[3][tid] + bc[tid];
}

extern "C" void kernel_launch(void* const* d_in, const int* in_sizes, int n_in,
                              void* d_out, int out_size, void* d_ws, size_t ws_size,
                              hipStream_t stream)
{
  const int*   ids    = (const int*)d_in[0];
  const int*   ngrams = (const int*)d_in[1];
  const float* tfidf  = (const float*)d_in[2];
  const float* emb    = (const float*)d_in[3];
  const float* pos    = (const float*)d_in[4];
  const float* bucket = (const float*)d_in[5];
  const float* Wq = (const float*)d_in[6];  const float* bq = (const float*)d_in[7];
  const float* Wk = (const float*)d_in[8];  const float* bk = (const float*)d_in[9];
  const float* Wv = (const float*)d_in[10]; const float* bv = (const float*)d_in[11];
  const float* Wo = (const float*)d_in[12]; const float* bo = (const float*)d_in[13];
  const float* g1 = (const float*)d_in[14]; const float* be1= (const float*)d_in[15];
  const float* g2 = (const float*)d_in[16]; const float* be2= (const float*)d_in[17];
  const float* W1 = (const float*)d_in[18]; const float* b1 = (const float*)d_in[19];
  const float* W2 = (const float*)d_in[20]; const float* b2 = (const float*)d_in[21];
  const float* alpha = (const float*)d_in[22];
  const float* gf = (const float*)d_in[23]; const float* bf = (const float*)d_in[24];
  const float* Wc = (const float*)d_in[25]; const float* bc = (const float*)d_in[26];

  uint8_t* base = (uint8_t*)d_ws;
  float*  x      = (float*)  base;                  //  8,388,608
  ushort* x2b    = (ushort*)(base + 8388608);       //  4,194,304
  ushort* qkb    = (ushort*)(base + 12582912);      //  8,388,608
  ushort* vtb    = (ushort*)(base + 20971520);      //  4,194,304
  ushort* attb   = (ushort*)(base + 25165824);      //  4,194,304
  ushort* midb   = (ushort*)(base + 29360128);      // 16,777,216
  float*  bm2    = (float*) (base + 46137344);      //     65,536 (2 layers)
  ushort* WqkvT  = (ushort*)(base + 46202880);      //    786,432
  ushort* WoT    = (ushort*)(base + 46989312);      //    262,144
  ushort* W1T    = (ushort*)(base + 47251456);      //  1,048,576
  ushort* W2T    = (ushort*)(base + 48300032);      //  1,048,576  -> 49,348,608 total

  TDescs td;
  for (int l = 0; l < NL; ++l) {
    td.d[6*l+0] = { Wq + (size_t)l*DIM*DIM, WqkvT + (size_t)l*768*DIM +   0*DIM, DIM, DIM };
    td.d[6*l+1] = { Wk + (size_t)l*DIM*DIM, WqkvT + (size_t)l*768*DIM + 256*DIM, DIM, DIM };
    td.d[6*l+2] = { Wv + (size_t)l*DIM*DIM, WqkvT + (size_t)l*768*DIM + 512*DIM, DIM, DIM };
    td.d[6*l+3] = { Wo + (size_t)l*DIM*DIM, WoT  + (size_t)l*DIM*DIM,  DIM, DIM };
    td.d[6*l+4] = { W1 + (size_t)l*DIM*FFD, W1T  + (size_t)l*FFD*DIM,  DIM, FFD };
    td.d[6*l+5] = { W2 + (size_t)l*FFD*DIM, W2T  + (size_t)l*DIM*FFD,  FFD, DIM };
  }
  transpose_conv<<<dim3(32, 32, 12), 256, 0, stream>>>(td);

  embed_kernel<<<TOK, 256, 0, stream>>>(ids, ngrams, tfidf, emb, pos, bucket, alpha, x, bm2);

  const dim3 gqkv(6, TOK/64), gff1(8, TOK/64), g256(2, TOK/64);
  const dim3 ga(SEQ/64, NH, 8);
  for (int l = 0; l < NL; ++l) {
    ln_bf16<<<TOK/4, 256, 0, stream>>>(x, g1 + l*DIM, be1 + l*DIM, x2b);
    gemm_mfma<256, 768, 3><<<gqkv, 256, 0, stream>>>(
        x2b, WqkvT + (size_t)l*768*DIM, bq + l*DIM, bk + l*DIM, bv + l*DIM, qkb, vtb);
    attn_mfma<<<ga, 256, 0, stream>>>(qkb, vtb, bm2 + l*TOK, attb);
    gemm_mfma<256, 256, 2><<<g256, 256, 0, stream>>>(
        attb, WoT + (size_t)l*DIM*DIM, bo + l*DIM, nullptr, nullptr, x, nullptr);
    ln_bf16<<<TOK/4, 256, 0, stream>>>(x, g2 + l*DIM, be2 + l*DIM, x2b);
    gemm_mfma<256, 1024, 1><<<gff1, 256, 0, stream>>>(
        x2b, W1T + (size_t)l*FFD*DIM, b1 + l*FFD, nullptr, nullptr, midb, nullptr);
    gemm_mfma<1024, 256, 2><<<g256, 256, 0, stream>>>(
        midb, W2T + (size_t)l*DIM*FFD, b2 + l*DIM, nullptr, nullptr, x, nullptr);
  }
  cls_kernel<<<8, 256, 0, stream>>>(x, gf, bf, Wc, bc, (float*)d_out);
}

// Round 5
// 265.110 us; speedup vs baseline: 1.3512x; 1.3512x over previous
//
#include <hip/hip_runtime.h>
#include <hip/hip_bf16.h>
#include <math.h>

#define TOK 8192       // B*S
#define DIM 256
#define SEQ 1024
#define NH 8
#define FFD 1024
#define NL 2
#define VOCAB 32000
#define QKSTRIDE 2097152   // elems between Q and K head-major blocks

typedef short bf16x8 __attribute__((ext_vector_type(8)));
typedef short bf16x4 __attribute__((ext_vector_type(4)));
typedef float f32x4 __attribute__((ext_vector_type(4)));

__device__ __forceinline__ ushort f2bf(float f) {
  union { float f; uint32_t u; } v; v.f = f;
  uint32_t r = v.u + 0x7FFFu + ((v.u >> 16) & 1u);
  return (ushort)(r >> 16);
}

__device__ __forceinline__ float exp2_n(float x) {
  float r; asm("v_exp_f32 %0, %1" : "=v"(r) : "v"(x)); return r;
}

__device__ __forceinline__ void gload_lds16(const ushort* gp, ushort* lp) {
  __builtin_amdgcn_global_load_lds(
      (const __attribute__((address_space(1))) void*)gp,
      (__attribute__((address_space(3))) void*)lp, 16, 0, 0);
}

// ---------------- embedding + ngram + per-layer base-2 tfidf bias ----------------
__global__ __launch_bounds__(256) void embed_kernel(
    const int* __restrict__ ids, const int* __restrict__ ngram_ids,
    const float* __restrict__ tfidf, const float* __restrict__ emb,
    const float* __restrict__ pos, const float* __restrict__ bucket,
    const float* __restrict__ alpha, float* __restrict__ x, float* __restrict__ bm2)
{
  __shared__ int ngs[12];
  const int t = blockIdx.x;
  const int id = ids[t];
  int idc = id; if (idc < 0) idc = 0; if (idc > VOCAB-1) idc = VOCAB-1;
  if (threadIdx.x < 12) ngs[threadIdx.x] = ngram_ids[idc*12 + threadIdx.x];
  if (threadIdx.x == 0) {
    const float tf = tfidf[idc];
    const bool msk = (id == 0);
    const float l2e = 1.4426950408889634f;
    bm2[t]       = msk ? -1e30f : tf * alpha[0] * l2e;
    bm2[TOK + t] = msk ? -1e30f : tf * alpha[1] * l2e;
  }
  __syncthreads();
  const int d = threadIdx.x;
  const int s = t & (SEQ - 1);
  float v = emb[(size_t)id*DIM + d] + pos[s*DIM + d];
  float sum = 0.f; int cnt = 0;
  #pragma unroll
  for (int g = 0; g < 12; ++g) {
    const int ng = ngs[g];
    if (ng != 0) { sum += bucket[(size_t)ng*DIM + d]; cnt++; }
  }
  v += sum / fmaxf((float)cnt, 1.0f);
  x[(size_t)t*DIM + d] = v;
}

// ---------------- layernorm -> bf16 ----------------
__global__ __launch_bounds__(256) void ln_bf16(
    const float* __restrict__ x, const float* __restrict__ g,
    const float* __restrict__ b, ushort* __restrict__ y)
{
  const int wave = threadIdx.x >> 6, lane = threadIdx.x & 63;
  const int row = blockIdx.x * 4 + wave;
  const float* xr = x + (size_t)row * DIM;
  float4 v = *reinterpret_cast<const float4*>(xr + lane*4);
  float s = v.x + v.y + v.z + v.w;
  #pragma unroll
  for (int o = 32; o >= 1; o >>= 1) s += __shfl_xor(s, o);
  const float mean = s * (1.f/256.f);
  const float dx0 = v.x-mean, dx1 = v.y-mean, dx2 = v.z-mean, dx3 = v.w-mean;
  float q = dx0*dx0 + dx1*dx1 + dx2*dx2 + dx3*dx3;
  #pragma unroll
  for (int o = 32; o >= 1; o >>= 1) q += __shfl_xor(q, o);
  const float rs = rsqrtf(q * (1.f/256.f) + 1e-5f);
  float4 gv = *reinterpret_cast<const float4*>(g + lane*4);
  float4 bv = *reinterpret_cast<const float4*>(b + lane*4);
  ushort4 o4;
  o4.x = f2bf(dx0*rs*gv.x + bv.x);
  o4.y = f2bf(dx1*rs*gv.y + bv.y);
  o4.z = f2bf(dx2*rs*gv.z + bv.z);
  o4.w = f2bf(dx3*rs*gv.w + bv.w);
  *reinterpret_cast<ushort4*>(y + (size_t)row*DIM + lane*4) = o4;
}

// ---------------- weight transpose + bf16: f32 [K][N] -> bf16 [N][K] ----------------
struct TDesc { const float* src; ushort* dst; int K; int N; };
struct TDescs { TDesc d[12]; };

__global__ __launch_bounds__(256) void transpose_conv(TDescs descs)
{
  const TDesc t = descs.d[blockIdx.z];
  const int k0 = blockIdx.x * 32, n0 = blockIdx.y * 32;
  if (k0 >= t.K || n0 >= t.N) return;
  __shared__ float tile[32][33];
  const int r = threadIdx.x >> 5, cc = threadIdx.x & 31;
  #pragma unroll
  for (int i = 0; i < 4; ++i)
    tile[r + i*8][cc] = t.src[(size_t)(k0 + r + i*8)*t.N + n0 + cc];
  __syncthreads();
  #pragma unroll
  for (int i = 0; i < 4; ++i)
    t.dst[(size_t)(n0 + r + i*8)*t.K + k0 + cc] = f2bf(tile[cc][r + i*8]);
}

// ---------------- bf16 MFMA GEMM: C[M,N] = A[M,K] @ B^T  (B as [N][K]) ----------------
// BM=64, BN=128, BK=32; 4 waves, wave w owns cols [w*32, w*32+32); frags 4x2.
// MODE 1: relu + bf16 out; MODE 2: f32 += ;
// MODE 3: qkv -> Q,K head-major [b][h][s][32] (Cout, +QKSTRIDE for K);
//         V permuted into vtb[b][h][sg][d][32 perm keys].
template<int KDIM, int NDIM, int MODE>
__global__ __launch_bounds__(256) void gemm_mfma(
    const ushort* __restrict__ A, const ushort* __restrict__ Bw,
    const float* __restrict__ bias0, const float* __restrict__ bias1,
    const float* __restrict__ bias2, void* __restrict__ Cout,
    ushort* __restrict__ vtb)
{
  __shared__ ushort Al[2][64*32];
  __shared__ ushort Bl[2][128*32];
  const int bm = blockIdx.y * 64, bn = blockIdx.x * 128;
  const int tid = threadIdx.x, w = tid >> 6, lane = tid & 63;
  const int g = lane >> 4, c = lane & 15;
  const int lrow = lane >> 2, lc8 = (lane & 3) * 8;
  const f32x4 fzero = {0.f, 0.f, 0.f, 0.f};
  f32x4 acc[4][2];
  #pragma unroll
  for (int m = 0; m < 4; ++m) { acc[m][0] = fzero; acc[m][1] = fzero; }

#define STAGE(buf, k0)                                                         \
  {                                                                            \
    _Pragma("unroll")                                                          \
    for (int ch = w; ch < 12; ch += 4) {                                       \
      if (ch < 4)                                                              \
        gload_lds16(A + (size_t)(bm + ch*16 + lrow)*KDIM + (k0) + lc8,         \
                    &Al[buf][ch*512]);                                         \
      else                                                                     \
        gload_lds16(Bw + (size_t)(bn + (ch-4)*16 + lrow)*KDIM + (k0) + lc8,    \
                    &Bl[buf][(ch-4)*512]);                                     \
    }                                                                          \
  }

  STAGE(0, 0);
  asm volatile("s_waitcnt vmcnt(0)");
  __syncthreads();
  int buf = 0;
  for (int k0 = 0; k0 < KDIM; k0 += 32) {
    if (k0 + 32 < KDIM) STAGE(buf^1, k0 + 32);
    bf16x8 af[4], bfr[2];
    #pragma unroll
    for (int m = 0; m < 4; ++m)
      af[m] = *(const bf16x8*)&Al[buf][(m*16 + c)*32 + g*8];
    #pragma unroll
    for (int n = 0; n < 2; ++n)
      bfr[n] = *(const bf16x8*)&Bl[buf][(w*32 + n*16 + c)*32 + g*8];
    #pragma unroll
    for (int m = 0; m < 4; ++m)
      #pragma unroll
      for (int n = 0; n < 2; ++n)
        acc[m][n] = __builtin_amdgcn_mfma_f32_16x16x32_bf16(af[m], bfr[n], acc[m][n], 0, 0, 0);
    asm volatile("s_waitcnt vmcnt(0)");
    __syncthreads();
    buf ^= 1;
  }
#undef STAGE

  #pragma unroll
  for (int m = 0; m < 4; ++m) {
    const int row0 = bm + m*16 + g*4;
    #pragma unroll
    for (int n = 0; n < 2; ++n) {
      const int col = bn + w*32 + n*16 + c;
      if (MODE == 2) {
        float* C = (float*)Cout;
        const float bb = bias0[col];
        #pragma unroll
        for (int r = 0; r < 4; ++r)
          C[(size_t)(row0 + r)*NDIM + col] += acc[m][n][r] + bb;
      } else if (MODE == 1) {
        const float bb = bias0[col];
        #pragma unroll
        for (int r = 0; r < 4; ++r) {
          const float vv = fmaxf(acc[m][n][r] + bb, 0.f);
          const float other = __shfl_xor(vv, 1);
          if ((c & 1) == 0) {
            const uint32_t word = (uint32_t)f2bf(vv) | ((uint32_t)f2bf(other) << 16);
            *(uint32_t*)((ushort*)Cout + (size_t)(row0 + r)*NDIM + col) = word;
          }
        }
      } else {  // MODE 3
        const int b_ = row0 >> 10, s = row0 & (SEQ - 1);
        if (col < 512) {
          const int hd = col & 255;
          const int hh = hd >> 5, d = hd & 31;
          const float bb = (col < 256) ? bias0[hd] : bias1[hd];
          ushort* dst = (ushort*)Cout + (col < 256 ? 0 : QKSTRIDE)
                      + (((size_t)(b_*NH + hh)*SEQ + s) << 5) + d;
          #pragma unroll
          for (int r = 0; r < 4; ++r) {
            const float vv = acc[m][n][r] + bb;
            const float other = __shfl_xor(vv, 1);
            if ((c & 1) == 0) {
              const uint32_t word = (uint32_t)f2bf(vv) | ((uint32_t)f2bf(other) << 16);
              *(uint32_t*)(dst + (r << 5)) = word;
            }
          }
        } else {
          // V: permuted k-slot layout. position p = g'*8 + hi*4 + rr <-> key 16*hi+4*g'+rr
          const int hd = col - 512;
          const int hh = hd >> 5, d = hd & 31;
          const float bb = bias2[hd];
          const int sg = s >> 5, a = (s & 31) >> 2;
          const int pbase = (a & 3)*8 + (a >> 2)*4;
          ushort4 w4;
          w4.x = f2bf(acc[m][n][0] + bb);
          w4.y = f2bf(acc[m][n][1] + bb);
          w4.z = f2bf(acc[m][n][2] + bb);
          w4.w = f2bf(acc[m][n][3] + bb);
          *(ushort4*)(vtb + (((size_t)((b_*NH + hh)*32 + sg)*32 + d) << 5) + pbase) = w4;
        }
      }
    }
  }
}

// ---------------- swapped-operand MFMA flash attention, coalesced reg-direct ----------------
// grid (16, 8, 8) remapped bijectively so each XCD owns 8 whole (b,h) pairs.
// 4 waves, each 16 q-rows (q = lane&15). All loads: 16B/lane, wave-contiguous 1KB.
__global__ __launch_bounds__(256) void attn_mfma(
    const ushort* __restrict__ qh, const ushort* __restrict__ kh,
    const ushort* __restrict__ vph, const float* __restrict__ bm2l,
    ushort* __restrict__ O)
{
  int lin = blockIdx.x + 16*blockIdx.y + 128*blockIdx.z;
  lin = ((lin & 7) << 7) + (lin >> 3);          // XCD-chunked, bijective (1024 % 8 == 0)
  const int qt = lin & 15, h = (lin >> 4) & 7, b = lin >> 7;
  const int qb = qt << 6;
  const float scale2 = 0.17677669529663687f * 1.4426950408889634f;  // rsqrt(32)*log2e
  const int tid = threadIdx.x, w = tid >> 6, lane = tid & 63;
  const int g = lane >> 4, c = lane & 15;
  const f32x4 fzero = {0.f, 0.f, 0.f, 0.f};
  const size_t bh = (size_t)(b*NH + h);

  const bf16x8 qf = *(const bf16x8*)(qh + ((bh*SEQ + qb + w*16 + c) << 5) + g*8);
  const ushort* kbase = kh  + ((bh*SEQ) << 5) + g*8;   // + key*32
  const ushort* vbase = vph + ((bh*SEQ) << 5) + g*8;   // + (sg*32 + d)*32
  const float*  bmb   = bm2l + b*SEQ;

  f32x4 oacc[2]; oacc[0] = fzero; oacc[1] = fzero;
  float m_run = -1e30f, l_run = 0.f;

  bf16x8 kfA[4], kfB[4];
  bf16x8 vfA[2][2], vfB[2][2];
  f32x4 bbA[4], bbB[4];

#define LOADT(kt, kf, vf, bb)                                                  \
  {                                                                            \
    _Pragma("unroll")                                                          \
    for (int ks = 0; ks < 4; ++ks) {                                           \
      kf[ks] = *(const bf16x8*)(kbase + (((kt) + ks*16 + c) << 5));            \
      bb[ks] = *(const f32x4*)(bmb + (kt) + ks*16 + g*4);                      \
    }                                                                          \
    _Pragma("unroll")                                                          \
    for (int ds_ = 0; ds_ < 2; ++ds_)                                          \
      _Pragma("unroll")                                                        \
      for (int sg = 0; sg < 2; ++sg)                                           \
        vf[ds_][sg] = *(const bf16x8*)(vbase +                                 \
            (((((kt) >> 5) + sg)*32 + ds_*16 + c) << 5));                      \
  }

#define ATILE(kf, vf, bb)                                                      \
  {                                                                            \
    f32x4 sf[4];                                                               \
    __builtin_amdgcn_s_setprio(1);                                             \
    _Pragma("unroll")                                                          \
    for (int ks = 0; ks < 4; ++ks)                                             \
      sf[ks] = __builtin_amdgcn_mfma_f32_16x16x32_bf16(kf[ks], qf, fzero, 0, 0, 0); \
    __builtin_amdgcn_s_setprio(0);                                             \
    float p[4][4];                                                             \
    _Pragma("unroll")                                                          \
    for (int ks = 0; ks < 4; ++ks)                                             \
      _Pragma("unroll")                                                        \
      for (int r = 0; r < 4; ++r)                                              \
        p[ks][r] = fmaf(sf[ks][r], scale2, bb[ks][r]);                         \
    float tmax = p[0][0];                                                      \
    _Pragma("unroll")                                                          \
    for (int ks = 0; ks < 4; ++ks)                                             \
      _Pragma("unroll")                                                        \
      for (int r = 0; r < 4; ++r)                                              \
        if (ks + r) tmax = fmaxf(tmax, p[ks][r]);                              \
    tmax = fmaxf(tmax, __shfl_xor(tmax, 16));                                  \
    tmax = fmaxf(tmax, __shfl_xor(tmax, 32));                                  \
    const float m_new = fmaxf(m_run, tmax);                                    \
    const float sc = exp2_n(m_run - m_new);                                    \
    m_run = m_new;                                                             \
    float lsum = 0.f;                                                          \
    bf16x8 pb0, pb1;                                                           \
    _Pragma("unroll")                                                          \
    for (int ks = 0; ks < 2; ++ks)                                             \
      _Pragma("unroll")                                                        \
      for (int r = 0; r < 4; ++r) {                                            \
        const float e = exp2_n(p[ks][r] - m_new);                              \
        lsum += e;                                                             \
        pb0[ks*4 + r] = (short)f2bf(e);                                        \
      }                                                                        \
    _Pragma("unroll")                                                          \
    for (int ks = 2; ks < 4; ++ks)                                             \
      _Pragma("unroll")                                                        \
      for (int r = 0; r < 4; ++r) {                                            \
        const float e = exp2_n(p[ks][r] - m_new);                              \
        lsum += e;                                                             \
        pb1[(ks-2)*4 + r] = (short)f2bf(e);                                    \
      }                                                                        \
    lsum += __shfl_xor(lsum, 16);                                              \
    lsum += __shfl_xor(lsum, 32);                                              \
    l_run = l_run * sc + lsum;                                                 \
    oacc[0] *= sc; oacc[1] *= sc;                                              \
    __builtin_amdgcn_s_setprio(1);                                             \
    oacc[0] = __builtin_amdgcn_mfma_f32_16x16x32_bf16(vf[0][0], pb0, oacc[0], 0, 0, 0); \
    oacc[1] = __builtin_amdgcn_mfma_f32_16x16x32_bf16(vf[1][0], pb0, oacc[1], 0, 0, 0); \
    oacc[0] = __builtin_amdgcn_mfma_f32_16x16x32_bf16(vf[0][1], pb1, oacc[0], 0, 0, 0); \
    oacc[1] = __builtin_amdgcn_mfma_f32_16x16x32_bf16(vf[1][1], pb1, oacc[1], 0, 0, 0); \
    __builtin_amdgcn_s_setprio(0);                                             \
  }

  LOADT(0, kfA, vfA, bbA);
  for (int kt = 0; kt < SEQ; kt += 128) {
    LOADT(kt + 64, kfB, vfB, bbB);
    ATILE(kfA, vfA, bbA);
    if (kt + 128 < SEQ) LOADT(kt + 128, kfA, vfA, bbA);
    ATILE(kfB, vfB, bbB);
  }
#undef LOADT
#undef ATILE

  // epilogue: lane (g,c) holds O[d = ds*16 + g*4 + r][q = c]
  const float inv = 1.f / l_run;
  ushort* orow = O + (size_t)(b*SEQ + qb + w*16 + c)*DIM + h*32 + g*4;
  #pragma unroll
  for (int ds_ = 0; ds_ < 2; ++ds_) {
    const uint32_t w0 = (uint32_t)f2bf(oacc[ds_][0]*inv) | ((uint32_t)f2bf(oacc[ds_][1]*inv) << 16);
    const uint32_t w1 = (uint32_t)f2bf(oacc[ds_][2]*inv) | ((uint32_t)f2bf(oacc[ds_][3]*inv) << 16);
    *(uint32_t*)(orow + ds_*16)     = w0;
    *(uint32_t*)(orow + ds_*16 + 2) = w1;
  }
}

// ---------------- final LN (row 0 per batch) + classifier ----------------
__global__ __launch_bounds__(256) void cls_kernel(
    const float* __restrict__ x, const float* __restrict__ gf,
    const float* __restrict__ bf, const float* __restrict__ Wc,
    const float* __restrict__ bc, float* __restrict__ out)
{
  const int b = blockIdx.x;
  const int tid = threadIdx.x;
  const int wave = tid >> 6, lane = tid & 63;
  const float* xr = x + (size_t)b * SEQ * DIM;
  const float v = xr[tid];
  __shared__ float redm[4], redv[4], redc[4][4];
  float s = v;
  #pragma unroll
  for (int o = 32; o >= 1; o >>= 1) s += __shfl_xor(s, o);
  if (lane == 0) redm[wave] = s;
  __syncthreads();
  const float mean = (redm[0]+redm[1]+redm[2]+redm[3]) * (1.f/256.f);
  const float dv = v - mean;
  float q = dv * dv;
  #pragma unroll
  for (int o = 32; o >= 1; o >>= 1) q += __shfl_xor(q, o);
  if (lane == 0) redv[wave] = q;
  __syncthreads();
  const float var = (redv[0]+redv[1]+redv[2]+redv[3]) * (1.f/256.f);
  const float rs = rsqrtf(var + 1e-5f);
  const float yn = dv*rs*gf[tid] + bf[tid];
  float pc[4];
  #pragma unroll
  for (int cc = 0; cc < 4; ++cc) pc[cc] = yn * Wc[tid*4 + cc];
  #pragma unroll
  for (int cc = 0; cc < 4; ++cc) {
    #pragma unroll
    for (int o = 32; o >= 1; o >>= 1) pc[cc] += __shfl_xor(pc[cc], o);
  }
  if (lane == 0) {
    #pragma unroll
    for (int cc = 0; cc < 4; ++cc) redc[wave][cc] = pc[cc];
  }
  __syncthreads();
  if (tid < 4)
    out[b*4 + tid] = redc[0][tid] + redc[1][tid] + redc[2][tid] + redc[3][tid] + bc[tid];
}

extern "C" void kernel_launch(void* const* d_in, const int* in_sizes, int n_in,
                              void* d_out, int out_size, void* d_ws, size_t ws_size,
                              hipStream_t stream)
{
  const int*   ids    = (const int*)d_in[0];
  const int*   ngrams = (const int*)d_in[1];
  const float* tfidf  = (const float*)d_in[2];
  const float* emb    = (const float*)d_in[3];
  const float* pos    = (const float*)d_in[4];
  const float* bucket = (const float*)d_in[5];
  const float* Wq = (const float*)d_in[6];  const float* bq = (const float*)d_in[7];
  const float* Wk = (const float*)d_in[8];  const float* bk = (const float*)d_in[9];
  const float* Wv = (const float*)d_in[10]; const float* bv = (const float*)d_in[11];
  const float* Wo = (const float*)d_in[12]; const float* bo = (const float*)d_in[13];
  const float* g1 = (const float*)d_in[14]; const float* be1= (const float*)d_in[15];
  const float* g2 = (const float*)d_in[16]; const float* be2= (const float*)d_in[17];
  const float* W1 = (const float*)d_in[18]; const float* b1 = (const float*)d_in[19];
  const float* W2 = (const float*)d_in[20]; const float* b2 = (const float*)d_in[21];
  const float* alpha = (const float*)d_in[22];
  const float* gf = (const float*)d_in[23]; const float* bf = (const float*)d_in[24];
  const float* Wc = (const float*)d_in[25]; const float* bc = (const float*)d_in[26];

  uint8_t* base = (uint8_t*)d_ws;
  float*  x      = (float*)  base;                  //  8,388,608
  ushort* x2b    = (ushort*)(base + 8388608);       //  4,194,304
  ushort* qkh    = (ushort*)(base + 12582912);      //  8,388,608 (Q head-major, K at +QKSTRIDE)
  ushort* vtb    = (ushort*)(base + 20971520);      //  4,194,304 (V permuted)
  ushort* attb   = (ushort*)(base + 25165824);      //  4,194,304
  ushort* midb   = (ushort*)(base + 29360128);      // 16,777,216
  float*  bm2    = (float*) (base + 46137344);      //     65,536 (2 layers)
  ushort* WqkvT  = (ushort*)(base + 46202880);      //    786,432
  ushort* WoT    = (ushort*)(base + 46989312);      //    262,144
  ushort* W1T    = (ushort*)(base + 47251456);      //  1,048,576
  ushort* W2T    = (ushort*)(base + 48300032);      //  1,048,576  -> 49,348,608 total

  TDescs td;
  for (int l = 0; l < NL; ++l) {
    td.d[6*l+0] = { Wq + (size_t)l*DIM*DIM, WqkvT + (size_t)l*768*DIM +   0*DIM, DIM, DIM };
    td.d[6*l+1] = { Wk + (size_t)l*DIM*DIM, WqkvT + (size_t)l*768*DIM + 256*DIM, DIM, DIM };
    td.d[6*l+2] = { Wv + (size_t)l*DIM*DIM, WqkvT + (size_t)l*768*DIM + 512*DIM, DIM, DIM };
    td.d[6*l+3] = { Wo + (size_t)l*DIM*DIM, WoT  + (size_t)l*DIM*DIM,  DIM, DIM };
    td.d[6*l+4] = { W1 + (size_t)l*DIM*FFD, W1T  + (size_t)l*FFD*DIM,  DIM, FFD };
    td.d[6*l+5] = { W2 + (size_t)l*FFD*DIM, W2T  + (size_t)l*DIM*FFD,  FFD, DIM };
  }
  transpose_conv<<<dim3(32, 32, 12), 256, 0, stream>>>(td);

  embed_kernel<<<TOK, 256, 0, stream>>>(ids, ngrams, tfidf, emb, pos, bucket, alpha, x, bm2);

  const dim3 gqkv(6, TOK/64), gff1(8, TOK/64), g256(2, TOK/64);
  const dim3 ga(SEQ/64, NH, 8);
  for (int l = 0; l < NL; ++l) {
    ln_bf16<<<TOK/4, 256, 0, stream>>>(x, g1 + l*DIM, be1 + l*DIM, x2b);
    gemm_mfma<256, 768, 3><<<gqkv, 256, 0, stream>>>(
        x2b, WqkvT + (size_t)l*768*DIM, bq + l*DIM, bk + l*DIM, bv + l*DIM, qkh, vtb);
    attn_mfma<<<ga, 256, 0, stream>>>(qkh, qkh + QKSTRIDE, vtb, bm2 + l*TOK, attb);
    gemm_mfma<256, 256, 2><<<g256, 256, 0, stream>>>(
        attb, WoT + (size_t)l*DIM*DIM, bo + l*DIM, nullptr, nullptr, x, nullptr);
    ln_bf16<<<TOK/4, 256, 0, stream>>>(x, g2 + l*DIM, be2 + l*DIM, x2b);
    gemm_mfma<256, 1024, 1><<<gff1, 256, 0, stream>>>(
        x2b, W1T + (size_t)l*FFD*DIM, b1 + l*FFD, nullptr, nullptr, midb, nullptr);
    gemm_mfma<1024, 256, 2><<<g256, 256, 0, stream>>>(
        midb, W2T + (size_t)l*DIM*FFD, b2 + l*DIM, nullptr, nullptr, x, nullptr);
  }
  cls_kernel<<<8, 256, 0, stream>>>(x, gf, bf, Wc, bc, (float*)d_out);
}

// Round 6
// 234.491 us; speedup vs baseline: 1.5276x; 1.1306x over previous
//
#include <hip/hip_runtime.h>
#include <hip/hip_bf16.h>
#include <math.h>

#define TOK 8192       // B*S
#define DIM 256
#define SEQ 1024
#define NH 8
#define FFD 1024
#define NL 2
#define VOCAB 32000
#define QKSTRIDE 2097152   // elems between Q and K head-major blocks

typedef short bf16x8 __attribute__((ext_vector_type(8)));
typedef short bf16x4 __attribute__((ext_vector_type(4)));
typedef float f32x4 __attribute__((ext_vector_type(4)));

__device__ __forceinline__ ushort f2bf(float f) {
  union { float f; uint32_t u; } v; v.f = f;
  uint32_t r = v.u + 0x7FFFu + ((v.u >> 16) & 1u);
  return (ushort)(r >> 16);
}

__device__ __forceinline__ float exp2_n(float x) {
  float r; asm("v_exp_f32 %0, %1" : "=v"(r) : "v"(x)); return r;
}

__device__ __forceinline__ uint32_t cvtpk(float lo, float hi) {
  uint32_t r; asm("v_cvt_pk_bf16_f32 %0, %1, %2" : "=v"(r) : "v"(lo), "v"(hi));
  return r;
}

__device__ __forceinline__ void gload_lds16(const ushort* gp, ushort* lp) {
  __builtin_amdgcn_global_load_lds(
      (const __attribute__((address_space(1))) void*)gp,
      (__attribute__((address_space(3))) void*)lp, 16, 0, 0);
}

// ---------------- embedding + ngram + per-layer base-2 tfidf bias ----------------
__global__ __launch_bounds__(256) void embed_kernel(
    const int* __restrict__ ids, const int* __restrict__ ngram_ids,
    const float* __restrict__ tfidf, const float* __restrict__ emb,
    const float* __restrict__ pos, const float* __restrict__ bucket,
    const float* __restrict__ alpha, float* __restrict__ x, float* __restrict__ bm2)
{
  __shared__ int ngs[12];
  const int t = blockIdx.x;
  const int id = ids[t];
  int idc = id; if (idc < 0) idc = 0; if (idc > VOCAB-1) idc = VOCAB-1;
  if (threadIdx.x < 12) ngs[threadIdx.x] = ngram_ids[idc*12 + threadIdx.x];
  if (threadIdx.x == 0) {
    const float tf = tfidf[idc];
    const bool msk = (id == 0);
    const float l2e = 1.4426950408889634f;
    bm2[t]       = msk ? -1e30f : tf * alpha[0] * l2e;
    bm2[TOK + t] = msk ? -1e30f : tf * alpha[1] * l2e;
  }
  __syncthreads();
  const int d = threadIdx.x;
  const int s = t & (SEQ - 1);
  float v = emb[(size_t)id*DIM + d] + pos[s*DIM + d];
  float sum = 0.f; int cnt = 0;
  #pragma unroll
  for (int g = 0; g < 12; ++g) {
    const int ng = ngs[g];
    if (ng != 0) { sum += bucket[(size_t)ng*DIM + d]; cnt++; }
  }
  v += sum / fmaxf((float)cnt, 1.0f);
  x[(size_t)t*DIM + d] = v;
}

// ---------------- layernorm -> bf16 ----------------
__global__ __launch_bounds__(256) void ln_bf16(
    const float* __restrict__ x, const float* __restrict__ g,
    const float* __restrict__ b, ushort* __restrict__ y)
{
  const int wave = threadIdx.x >> 6, lane = threadIdx.x & 63;
  const int row = blockIdx.x * 4 + wave;
  const float* xr = x + (size_t)row * DIM;
  float4 v = *reinterpret_cast<const float4*>(xr + lane*4);
  float s = v.x + v.y + v.z + v.w;
  #pragma unroll
  for (int o = 32; o >= 1; o >>= 1) s += __shfl_xor(s, o);
  const float mean = s * (1.f/256.f);
  const float dx0 = v.x-mean, dx1 = v.y-mean, dx2 = v.z-mean, dx3 = v.w-mean;
  float q = dx0*dx0 + dx1*dx1 + dx2*dx2 + dx3*dx3;
  #pragma unroll
  for (int o = 32; o >= 1; o >>= 1) q += __shfl_xor(q, o);
  const float rs = rsqrtf(q * (1.f/256.f) + 1e-5f);
  float4 gv = *reinterpret_cast<const float4*>(g + lane*4);
  float4 bv = *reinterpret_cast<const float4*>(b + lane*4);
  ushort4 o4;
  o4.x = f2bf(dx0*rs*gv.x + bv.x);
  o4.y = f2bf(dx1*rs*gv.y + bv.y);
  o4.z = f2bf(dx2*rs*gv.z + bv.z);
  o4.w = f2bf(dx3*rs*gv.w + bv.w);
  *reinterpret_cast<ushort4*>(y + (size_t)row*DIM + lane*4) = o4;
}

// ---------------- weight transpose + bf16: f32 [K][N] -> bf16 [N][K] ----------------
struct TDesc { const float* src; ushort* dst; int K; int N; };
struct TDescs { TDesc d[12]; };

__global__ __launch_bounds__(256) void transpose_conv(TDescs descs)
{
  const TDesc t = descs.d[blockIdx.z];
  const int k0 = blockIdx.x * 32, n0 = blockIdx.y * 32;
  if (k0 >= t.K || n0 >= t.N) return;
  __shared__ float tile[32][33];
  const int r = threadIdx.x >> 5, cc = threadIdx.x & 31;
  #pragma unroll
  for (int i = 0; i < 4; ++i)
    tile[r + i*8][cc] = t.src[(size_t)(k0 + r + i*8)*t.N + n0 + cc];
  __syncthreads();
  #pragma unroll
  for (int i = 0; i < 4; ++i)
    t.dst[(size_t)(n0 + r + i*8)*t.K + k0 + cc] = f2bf(tile[cc][r + i*8]);
}

// ---------------- bf16 MFMA GEMM: C[M,N] = A[M,K] @ B^T  (B as [N][K]) ----------------
// BM=64, BN=128, BK=32; 4 waves, wave w owns cols [w*32, w*32+32); frags 4x2.
// MODE 1: relu + bf16 out;
// MODE 3: qkv -> Q,K head-major [b][h][s][32] (Cout, +QKSTRIDE for K);
//         V permuted into vtb[b][h][sg][d][32 perm keys].
template<int KDIM, int NDIM, int MODE>
__global__ __launch_bounds__(256) void gemm_mfma(
    const ushort* __restrict__ A, const ushort* __restrict__ Bw,
    const float* __restrict__ bias0, const float* __restrict__ bias1,
    const float* __restrict__ bias2, void* __restrict__ Cout,
    ushort* __restrict__ vtb)
{
  __shared__ ushort Al[2][64*32];
  __shared__ ushort Bl[2][128*32];
  const int bm = blockIdx.y * 64, bn = blockIdx.x * 128;
  const int tid = threadIdx.x, w = tid >> 6, lane = tid & 63;
  const int g = lane >> 4, c = lane & 15;
  const int lrow = lane >> 2, lc8 = (lane & 3) * 8;
  const f32x4 fzero = {0.f, 0.f, 0.f, 0.f};
  f32x4 acc[4][2];
  #pragma unroll
  for (int m = 0; m < 4; ++m) { acc[m][0] = fzero; acc[m][1] = fzero; }

#define STAGE(buf, k0)                                                         \
  {                                                                            \
    _Pragma("unroll")                                                          \
    for (int ch = w; ch < 12; ch += 4) {                                       \
      if (ch < 4)                                                              \
        gload_lds16(A + (size_t)(bm + ch*16 + lrow)*KDIM + (k0) + lc8,         \
                    &Al[buf][ch*512]);                                         \
      else                                                                     \
        gload_lds16(Bw + (size_t)(bn + (ch-4)*16 + lrow)*KDIM + (k0) + lc8,    \
                    &Bl[buf][(ch-4)*512]);                                     \
    }                                                                          \
  }

  STAGE(0, 0);
  asm volatile("s_waitcnt vmcnt(0)");
  __syncthreads();
  int buf = 0;
  for (int k0 = 0; k0 < KDIM; k0 += 32) {
    if (k0 + 32 < KDIM) STAGE(buf^1, k0 + 32);
    bf16x8 af[4], bfr[2];
    #pragma unroll
    for (int m = 0; m < 4; ++m)
      af[m] = *(const bf16x8*)&Al[buf][(m*16 + c)*32 + g*8];
    #pragma unroll
    for (int n = 0; n < 2; ++n)
      bfr[n] = *(const bf16x8*)&Bl[buf][(w*32 + n*16 + c)*32 + g*8];
    #pragma unroll
    for (int m = 0; m < 4; ++m)
      #pragma unroll
      for (int n = 0; n < 2; ++n)
        acc[m][n] = __builtin_amdgcn_mfma_f32_16x16x32_bf16(af[m], bfr[n], acc[m][n], 0, 0, 0);
    asm volatile("s_waitcnt vmcnt(0)");
    __syncthreads();
    buf ^= 1;
  }
#undef STAGE

  #pragma unroll
  for (int m = 0; m < 4; ++m) {
    const int row0 = bm + m*16 + g*4;
    #pragma unroll
    for (int n = 0; n < 2; ++n) {
      const int col = bn + w*32 + n*16 + c;
      if (MODE == 1) {
        const float bb = bias0[col];
        #pragma unroll
        for (int r = 0; r < 4; ++r) {
          const float vv = fmaxf(acc[m][n][r] + bb, 0.f);
          const float other = __shfl_xor(vv, 1);
          if ((c & 1) == 0) {
            const uint32_t word = (uint32_t)f2bf(vv) | ((uint32_t)f2bf(other) << 16);
            *(uint32_t*)((ushort*)Cout + (size_t)(row0 + r)*NDIM + col) = word;
          }
        }
      } else {  // MODE 3
        const int b_ = row0 >> 10, s = row0 & (SEQ - 1);
        if (col < 512) {
          const int hd = col & 255;
          const int hh = hd >> 5, d = hd & 31;
          const float bb = (col < 256) ? bias0[hd] : bias1[hd];
          ushort* dst = (ushort*)Cout + (col < 256 ? 0 : QKSTRIDE)
                      + (((size_t)(b_*NH + hh)*SEQ + s) << 5) + d;
          #pragma unroll
          for (int r = 0; r < 4; ++r) {
            const float vv = acc[m][n][r] + bb;
            const float other = __shfl_xor(vv, 1);
            if ((c & 1) == 0) {
              const uint32_t word = (uint32_t)f2bf(vv) | ((uint32_t)f2bf(other) << 16);
              *(uint32_t*)(dst + (r << 5)) = word;
            }
          }
        } else {
          // V: permuted k-slot layout. position p = g'*8 + hi*4 + rr <-> key 16*hi+4*g'+rr
          const int hd = col - 512;
          const int hh = hd >> 5, d = hd & 31;
          const float bb = bias2[hd];
          const int sg = s >> 5, a = (s & 31) >> 2;
          const int pbase = (a & 3)*8 + (a >> 2)*4;
          ushort4 w4;
          w4.x = f2bf(acc[m][n][0] + bb);
          w4.y = f2bf(acc[m][n][1] + bb);
          w4.z = f2bf(acc[m][n][2] + bb);
          w4.w = f2bf(acc[m][n][3] + bb);
          *(ushort4*)(vtb + (((size_t)((b_*NH + hh)*32 + sg)*32 + d) << 5) + pbase) = w4;
        }
      }
    }
  }
}

// ---------------- 64x64-tile accumulate GEMM (N=256): C[M,256] += A@B^T + bias ----------------
// 4 waves in 2x2; each wave 32x32 (2x2 frags). grid (4, M/64) = 512 blocks.
template<int KDIM>
__global__ __launch_bounds__(256) void gemm64_acc(
    const ushort* __restrict__ A, const ushort* __restrict__ Bw,
    const float* __restrict__ bias, float* __restrict__ C)
{
  __shared__ ushort Al[2][64*32];
  __shared__ ushort Bl[2][64*32];
  const int bm = blockIdx.y * 64, bn = blockIdx.x * 64;
  const int tid = threadIdx.x, w = tid >> 6, lane = tid & 63;
  const int wm = w >> 1, wn = w & 1;
  const int g = lane >> 4, c = lane & 15;
  const int lrow = tid >> 2, lc8 = (tid & 3) * 8;
  const f32x4 fzero = {0.f, 0.f, 0.f, 0.f};
  f32x4 acc[2][2];
  acc[0][0] = fzero; acc[0][1] = fzero; acc[1][0] = fzero; acc[1][1] = fzero;

#define STAGE64(buf, k0)                                                       \
  {                                                                            \
    gload_lds16(A  + (size_t)(bm + lrow)*KDIM + (k0) + lc8,                    \
                &Al[buf][lrow*32 + lc8]);                                      \
    gload_lds16(Bw + (size_t)(bn + lrow)*KDIM + (k0) + lc8,                    \
                &Bl[buf][lrow*32 + lc8]);                                      \
  }

  STAGE64(0, 0);
  asm volatile("s_waitcnt vmcnt(0)");
  __syncthreads();
  int buf = 0;
  for (int k0 = 0; k0 < KDIM; k0 += 32) {
    if (k0 + 32 < KDIM) STAGE64(buf^1, k0 + 32);
    bf16x8 af[2], bfr[2];
    #pragma unroll
    for (int m = 0; m < 2; ++m)
      af[m] = *(const bf16x8*)&Al[buf][(wm*32 + m*16 + c)*32 + g*8];
    #pragma unroll
    for (int n = 0; n < 2; ++n)
      bfr[n] = *(const bf16x8*)&Bl[buf][(wn*32 + n*16 + c)*32 + g*8];
    #pragma unroll
    for (int m = 0; m < 2; ++m)
      #pragma unroll
      for (int n = 0; n < 2; ++n)
        acc[m][n] = __builtin_amdgcn_mfma_f32_16x16x32_bf16(af[m], bfr[n], acc[m][n], 0, 0, 0);
    asm volatile("s_waitcnt vmcnt(0)");
    __syncthreads();
    buf ^= 1;
  }
#undef STAGE64

  #pragma unroll
  for (int m = 0; m < 2; ++m) {
    const int row0 = bm + wm*32 + m*16 + g*4;
    #pragma unroll
    for (int n = 0; n < 2; ++n) {
      const int col = bn + wn*32 + n*16 + c;
      const float bb = bias[col];
      #pragma unroll
      for (int r = 0; r < 4; ++r)
        C[(size_t)(row0 + r)*DIM + col] += acc[m][n][r] + bb;
    }
  }
}

// ---------------- swapped-operand MFMA flash attention, lane-local softmax ----------------
// grid 2048 x 128 threads (2 independent waves); bijective XCD chunking.
// Each wave: 16 q-rows (q = lane&15), 16 tiles of 64 keys, A/B register prefetch.
// Defer-max (THR=8, base-2 domain) + deferred l-reduction: steady-state tile has
// ZERO cross-lane ops (softmax entirely lane-local; P packed via v_cvt_pk_bf16_f32).
__global__ __launch_bounds__(128) void attn_mfma(
    const ushort* __restrict__ qh, const ushort* __restrict__ kh,
    const ushort* __restrict__ vph, const float* __restrict__ bm2l,
    ushort* __restrict__ O)
{
  const int bid = blockIdx.x;
  const int lin = ((bid & 7) << 8) + (bid >> 3);       // bijective (2048 % 8 == 0)
  const int tid = threadIdx.x, w = tid >> 6, lane = tid & 63;
  const int idx = lin*2 + w;                            // [0, 4096)
  const int qw = idx & 63, h = (idx >> 6) & 7, b = idx >> 9;
  const int qb = qw << 4;
  const float scale2 = 0.17677669529663687f * 1.4426950408889634f;  // rsqrt(32)*log2e
  const int g = lane >> 4, c = lane & 15;
  const f32x4 fzero = {0.f, 0.f, 0.f, 0.f};
  const size_t bh = (size_t)(b*NH + h);

  const bf16x8 qf = *(const bf16x8*)(qh + ((bh*SEQ + qb + c) << 5) + g*8);
  const ushort* kbase = kh  + ((bh*SEQ) << 5) + g*8;   // + key*32
  const ushort* vbase = vph + ((bh*SEQ) << 5) + g*8;   // + (sg*32 + d)*32
  const float*  bmb   = bm2l + b*SEQ;

  f32x4 oacc[2]; oacc[0] = fzero; oacc[1] = fzero;
  float m_run = -1e30f, l_part = 0.f;

  bf16x8 kfA[4], kfB[4];
  bf16x8 vfA[2][2], vfB[2][2];
  f32x4 bbA[4], bbB[4];

#define LOADT(kt, kf, vf, bb)                                                  \
  {                                                                            \
    _Pragma("unroll")                                                          \
    for (int ks = 0; ks < 4; ++ks) {                                           \
      kf[ks] = *(const bf16x8*)(kbase + (((kt) + ks*16 + c) << 5));            \
      bb[ks] = *(const f32x4*)(bmb + (kt) + ks*16 + g*4);                      \
    }                                                                          \
    _Pragma("unroll")                                                          \
    for (int ds_ = 0; ds_ < 2; ++ds_)                                          \
      _Pragma("unroll")                                                        \
      for (int sg = 0; sg < 2; ++sg)                                           \
        vf[ds_][sg] = *(const bf16x8*)(vbase +                                 \
            (((((kt) >> 5) + sg)*32 + ds_*16 + c) << 5));                      \
  }

#define ATILE(kf, vf, bb)                                                      \
  {                                                                            \
    f32x4 sf[4];                                                               \
    __builtin_amdgcn_s_setprio(1);                                             \
    _Pragma("unroll")                                                          \
    for (int ks = 0; ks < 4; ++ks)                                             \
      sf[ks] = __builtin_amdgcn_mfma_f32_16x16x32_bf16(kf[ks], qf, fzero, 0, 0, 0); \
    __builtin_amdgcn_s_setprio(0);                                             \
    float p[4][4];                                                             \
    _Pragma("unroll")                                                          \
    for (int ks = 0; ks < 4; ++ks)                                             \
      _Pragma("unroll")                                                        \
      for (int r = 0; r < 4; ++r)                                              \
        p[ks][r] = fmaf(sf[ks][r], scale2, bb[ks][r]);                         \
    /* lane-local max over 16 */                                               \
    float mx0 = fmaxf(fmaxf(p[0][0], p[0][1]), fmaxf(p[0][2], p[0][3]));       \
    float mx1 = fmaxf(fmaxf(p[1][0], p[1][1]), fmaxf(p[1][2], p[1][3]));       \
    float mx2 = fmaxf(fmaxf(p[2][0], p[2][1]), fmaxf(p[2][2], p[2][3]));       \
    float mx3 = fmaxf(fmaxf(p[3][0], p[3][1]), fmaxf(p[3][2], p[3][3]));       \
    const float pmax = fmaxf(fmaxf(mx0, mx1), fmaxf(mx2, mx3));                \
    if (!__all(pmax <= m_run + 8.f)) {                                         \
      float tmax = pmax;                                                       \
      tmax = fmaxf(tmax, __shfl_xor(tmax, 16));                                \
      tmax = fmaxf(tmax, __shfl_xor(tmax, 32));                                \
      const float m_new = fmaxf(m_run, tmax);                                  \
      const float sc = exp2_n(m_run - m_new);                                  \
      m_run = m_new;                                                           \
      l_part *= sc;                                                            \
      oacc[0] *= sc; oacc[1] *= sc;                                            \
    }                                                                          \
    float e[4][4];                                                             \
    _Pragma("unroll")                                                          \
    for (int ks = 0; ks < 4; ++ks)                                             \
      _Pragma("unroll")                                                        \
      for (int r = 0; r < 4; ++r)                                              \
        e[ks][r] = exp2_n(p[ks][r] - m_run);                                   \
    float s0 = 0.f, s1 = 0.f, s2 = 0.f, s3 = 0.f;                              \
    _Pragma("unroll")                                                          \
    for (int r = 0; r < 4; ++r) {                                              \
      s0 += e[0][r]; s1 += e[1][r]; s2 += e[2][r]; s3 += e[3][r];              \
    }                                                                          \
    l_part += (s0 + s1) + (s2 + s3);                                           \
    union { bf16x8 v; uint32_t u[4]; } pb0, pb1;                               \
    pb0.u[0] = cvtpk(e[0][0], e[0][1]); pb0.u[1] = cvtpk(e[0][2], e[0][3]);    \
    pb0.u[2] = cvtpk(e[1][0], e[1][1]); pb0.u[3] = cvtpk(e[1][2], e[1][3]);    \
    pb1.u[0] = cvtpk(e[2][0], e[2][1]); pb1.u[1] = cvtpk(e[2][2], e[2][3]);    \
    pb1.u[2] = cvtpk(e[3][0], e[3][1]); pb1.u[3] = cvtpk(e[3][2], e[3][3]);    \
    __builtin_amdgcn_s_setprio(1);                                             \
    oacc[0] = __builtin_amdgcn_mfma_f32_16x16x32_bf16(vf[0][0], pb0.v, oacc[0], 0, 0, 0); \
    oacc[1] = __builtin_amdgcn_mfma_f32_16x16x32_bf16(vf[1][0], pb0.v, oacc[1], 0, 0, 0); \
    oacc[0] = __builtin_amdgcn_mfma_f32_16x16x32_bf16(vf[0][1], pb1.v, oacc[0], 0, 0, 0); \
    oacc[1] = __builtin_amdgcn_mfma_f32_16x16x32_bf16(vf[1][1], pb1.v, oacc[1], 0, 0, 0); \
    __builtin_amdgcn_s_setprio(0);                                             \
  }

  LOADT(0, kfA, vfA, bbA);
  for (int kt = 0; kt < SEQ; kt += 128) {
    LOADT(kt + 64, kfB, vfB, bbB);
    ATILE(kfA, vfA, bbA);
    if (kt + 128 < SEQ) LOADT(kt + 128, kfA, vfA, bbA);
    ATILE(kfB, vfB, bbB);
  }
#undef LOADT
#undef ATILE

  // final l reduction across the 4 g-lanes sharing q=c
  float l_run = l_part;
  l_run += __shfl_xor(l_run, 16);
  l_run += __shfl_xor(l_run, 32);
  const float inv = 1.f / l_run;
  // epilogue: lane (g,c) holds O[d = ds*16 + g*4 + r][q = c]
  ushort* orow = O + (size_t)(b*SEQ + qb + c)*DIM + h*32 + g*4;
  #pragma unroll
  for (int ds_ = 0; ds_ < 2; ++ds_) {
    const uint32_t w0 = (uint32_t)f2bf(oacc[ds_][0]*inv) | ((uint32_t)f2bf(oacc[ds_][1]*inv) << 16);
    const uint32_t w1 = (uint32_t)f2bf(oacc[ds_][2]*inv) | ((uint32_t)f2bf(oacc[ds_][3]*inv) << 16);
    *(uint32_t*)(orow + ds_*16)     = w0;
    *(uint32_t*)(orow + ds_*16 + 2) = w1;
  }
}

// ---------------- final LN (row 0 per batch) + classifier ----------------
__global__ __launch_bounds__(256) void cls_kernel(
    const float* __restrict__ x, const float* __restrict__ gf,
    const float* __restrict__ bf, const float* __restrict__ Wc,
    const float* __restrict__ bc, float* __restrict__ out)
{
  const int b = blockIdx.x;
  const int tid = threadIdx.x;
  const int wave = tid >> 6, lane = tid & 63;
  const float* xr = x + (size_t)b * SEQ * DIM;
  const float v = xr[tid];
  __shared__ float redm[4], redv[4], redc[4][4];
  float s = v;
  #pragma unroll
  for (int o = 32; o >= 1; o >>= 1) s += __shfl_xor(s, o);
  if (lane == 0) redm[wave] = s;
  __syncthreads();
  const float mean = (redm[0]+redm[1]+redm[2]+redm[3]) * (1.f/256.f);
  const float dv = v - mean;
  float q = dv * dv;
  #pragma unroll
  for (int o = 32; o >= 1; o >>= 1) q += __shfl_xor(q, o);
  if (lane == 0) redv[wave] = q;
  __syncthreads();
  const float var = (redv[0]+redv[1]+redv[2]+redv[3]) * (1.f/256.f);
  const float rs = rsqrtf(var + 1e-5f);
  const float yn = dv*rs*gf[tid] + bf[tid];
  float pc[4];
  #pragma unroll
  for (int cc = 0; cc < 4; ++cc) pc[cc] = yn * Wc[tid*4 + cc];
  #pragma unroll
  for (int cc = 0; cc < 4; ++cc) {
    #pragma unroll
    for (int o = 32; o >= 1; o >>= 1) pc[cc] += __shfl_xor(pc[cc], o);
  }
  if (lane == 0) {
    #pragma unroll
    for (int cc = 0; cc < 4; ++cc) redc[wave][cc] = pc[cc];
  }
  __syncthreads();
  if (tid < 4)
    out[b*4 + tid] = redc[0][tid] + redc[1][tid] + redc[2][tid] + redc[3][tid] + bc[tid];
}

extern "C" void kernel_launch(void* const* d_in, const int* in_sizes, int n_in,
                              void* d_out, int out_size, void* d_ws, size_t ws_size,
                              hipStream_t stream)
{
  const int*   ids    = (const int*)d_in[0];
  const int*   ngrams = (const int*)d_in[1];
  const float* tfidf  = (const float*)d_in[2];
  const float* emb    = (const float*)d_in[3];
  const float* pos    = (const float*)d_in[4];
  const float* bucket = (const float*)d_in[5];
  const float* Wq = (const float*)d_in[6];  const float* bq = (const float*)d_in[7];
  const float* Wk = (const float*)d_in[8];  const float* bk = (const float*)d_in[9];
  const float* Wv = (const float*)d_in[10]; const float* bv = (const float*)d_in[11];
  const float* Wo = (const float*)d_in[12]; const float* bo = (const float*)d_in[13];
  const float* g1 = (const float*)d_in[14]; const float* be1= (const float*)d_in[15];
  const float* g2 = (const float*)d_in[16]; const float* be2= (const float*)d_in[17];
  const float* W1 = (const float*)d_in[18]; const float* b1 = (const float*)d_in[19];
  const float* W2 = (const float*)d_in[20]; const float* b2 = (const float*)d_in[21];
  const float* alpha = (const float*)d_in[22];
  const float* gf = (const float*)d_in[23]; const float* bf = (const float*)d_in[24];
  const float* Wc = (const float*)d_in[25]; const float* bc = (const float*)d_in[26];

  uint8_t* base = (uint8_t*)d_ws;
  float*  x      = (float*)  base;                  //  8,388,608
  ushort* x2b    = (ushort*)(base + 8388608);       //  4,194,304
  ushort* qkh    = (ushort*)(base + 12582912);      //  8,388,608 (Q head-major, K at +QKSTRIDE)
  ushort* vtb    = (ushort*)(base + 20971520);      //  4,194,304 (V permuted)
  ushort* attb   = (ushort*)(base + 25165824);      //  4,194,304
  ushort* midb   = (ushort*)(base + 29360128);      // 16,777,216
  float*  bm2    = (float*) (base + 46137344);      //     65,536 (2 layers)
  ushort* WqkvT  = (ushort*)(base + 46202880);      //    786,432
  ushort* WoT    = (ushort*)(base + 46989312);      //    262,144
  ushort* W1T    = (ushort*)(base + 47251456);      //  1,048,576
  ushort* W2T    = (ushort*)(base + 48300032);      //  1,048,576  -> 49,348,608 total

  TDescs td;
  for (int l = 0; l < NL; ++l) {
    td.d[6*l+0] = { Wq + (size_t)l*DIM*DIM, WqkvT + (size_t)l*768*DIM +   0*DIM, DIM, DIM };
    td.d[6*l+1] = { Wk + (size_t)l*DIM*DIM, WqkvT + (size_t)l*768*DIM + 256*DIM, DIM, DIM };
    td.d[6*l+2] = { Wv + (size_t)l*DIM*DIM, WqkvT + (size_t)l*768*DIM + 512*DIM, DIM, DIM };
    td.d[6*l+3] = { Wo + (size_t)l*DIM*DIM, WoT  + (size_t)l*DIM*DIM,  DIM, DIM };
    td.d[6*l+4] = { W1 + (size_t)l*DIM*FFD, W1T  + (size_t)l*FFD*DIM,  DIM, FFD };
    td.d[6*l+5] = { W2 + (size_t)l*FFD*DIM, W2T  + (size_t)l*DIM*FFD,  FFD, DIM };
  }
  transpose_conv<<<dim3(32, 32, 12), 256, 0, stream>>>(td);

  embed_kernel<<<TOK, 256, 0, stream>>>(ids, ngrams, tfidf, emb, pos, bucket, alpha, x, bm2);

  const dim3 gqkv(6, TOK/64), gff1(8, TOK/64), g64(4, TOK/64);
  for (int l = 0; l < NL; ++l) {
    ln_bf16<<<TOK/4, 256, 0, stream>>>(x, g1 + l*DIM, be1 + l*DIM, x2b);
    gemm_mfma<256, 768, 3><<<gqkv, 256, 0, stream>>>(
        x2b, WqkvT + (size_t)l*768*DIM, bq + l*DIM, bk + l*DIM, bv + l*DIM, qkh, vtb);
    attn_mfma<<<2048, 128, 0, stream>>>(qkh, qkh + QKSTRIDE, vtb, bm2 + l*TOK, attb);
    gemm64_acc<256><<<g64, 256, 0, stream>>>(
        attb, WoT + (size_t)l*DIM*DIM, bo + l*DIM, x);
    ln_bf16<<<TOK/4, 256, 0, stream>>>(x, g2 + l*DIM, be2 + l*DIM, x2b);
    gemm_mfma<256, 1024, 1><<<gff1, 256, 0, stream>>>(
        x2b, W1T + (size_t)l*FFD*DIM, b1 + l*FFD, nullptr, nullptr, midb, nullptr);
    gemm64_acc<1024><<<g64, 256, 0, stream>>>(
        midb, W2T + (size_t)l*DIM*FFD, b2 + l*DIM, x);
  }
  cls_kernel<<<8, 256, 0, stream>>>(x, gf, bf, Wc, bc, (float*)d_out);
}